// Round 1
// baseline (1084.765 us; speedup 1.0000x reference)
//
#include <hip/hip_runtime.h>

// Problem constants (fixed by the reference)
#define U_N   100000
#define I_N   50000
#define NTOT  150000          // U_N + I_N
#define DIM   64
#define NNZ   4800000
#define NM    (NTOT * DIM)    // 9,600,000 floats per output half

// scan config: 256 threads x 4 items = 1024 counts per block
#define SCAN_T     256
#define SCAN_ITEMS 4
#define SCAN_CHUNK (SCAN_T * SCAN_ITEMS)
#define SCAN_NB    ((NTOT + SCAN_CHUNK - 1) / SCAN_CHUNK)   // 147 (<= 256)

// ---------------------------------------------------------------------------
// 1) histogram of edge rows
__global__ void hist_kernel(const int* __restrict__ row, int* __restrict__ counts) {
    int i = blockIdx.x * blockDim.x + threadIdx.x;
    int stride = gridDim.x * blockDim.x;
    for (; i < NNZ; i += stride) atomicAdd(&counts[row[i]], 1);
}

// 2a) per-block reduce of counts -> bsum[block]
__global__ void scan_reduce(const int* __restrict__ counts, int* __restrict__ bsum) {
    __shared__ int sm[SCAN_T];
    int b = blockIdx.x, t = threadIdx.x;
    int base = b * SCAN_CHUNK + t * SCAN_ITEMS;
    int s = 0;
#pragma unroll
    for (int k = 0; k < SCAN_ITEMS; ++k) {
        int idx = base + k;
        s += (idx < NTOT) ? counts[idx] : 0;
    }
    sm[t] = s; __syncthreads();
    for (int off = SCAN_T / 2; off > 0; off >>= 1) {
        if (t < off) sm[t] += sm[t + off];
        __syncthreads();
    }
    if (t == 0) bsum[b] = sm[0];
}

// 2b) single-block exclusive scan of block sums -> boff[block]
__global__ void scan_partials(const int* __restrict__ bsum, int* __restrict__ boff,
                              int* __restrict__ rowptr) {
    __shared__ int sm[SCAN_T];
    int t = threadIdx.x;
    int v = (t < SCAN_NB) ? bsum[t] : 0;
    sm[t] = v; __syncthreads();
    for (int off = 1; off < SCAN_T; off <<= 1) {
        int add = (t >= off) ? sm[t - off] : 0;
        __syncthreads();
        sm[t] += add;
        __syncthreads();
    }
    if (t < SCAN_NB) boff[t] = sm[t] - v;   // exclusive
    if (t == 0) rowptr[NTOT] = NNZ;
}

// 2c) per-block exclusive scan + global offset -> rowptr
__global__ void scan_final(const int* __restrict__ counts, const int* __restrict__ boff,
                           int* __restrict__ rowptr) {
    __shared__ int sm[SCAN_T];
    int b = blockIdx.x, t = threadIdx.x;
    int base = b * SCAN_CHUNK + t * SCAN_ITEMS;
    int c[SCAN_ITEMS];
    int s = 0;
#pragma unroll
    for (int k = 0; k < SCAN_ITEMS; ++k) {
        int idx = base + k;
        c[k] = (idx < NTOT) ? counts[idx] : 0;
        s += c[k];
    }
    sm[t] = s; __syncthreads();
    int v = s;
    for (int off = 1; off < SCAN_T; off <<= 1) {
        int add = (t >= off) ? sm[t - off] : 0;
        __syncthreads();
        sm[t] += add;
        __syncthreads();
    }
    int ex = sm[t] - v + boff[b];
#pragma unroll
    for (int k = 0; k < SCAN_ITEMS; ++k) {
        int idx = base + k;
        if (idx < NTOT) { rowptr[idx] = ex; ex += c[k]; }
    }
}

// 3) scatter edges into CSR order: colval[pos] = (col, val)
__global__ void scatter_kernel(const int* __restrict__ row, const int* __restrict__ col,
                               const float* __restrict__ val, const int* __restrict__ rowptr,
                               int* __restrict__ cursor, int2* __restrict__ colval) {
    int i = blockIdx.x * blockDim.x + threadIdx.x;
    int stride = gridDim.x * blockDim.x;
    for (; i < NNZ; i += stride) {
        int r = row[i];
        int pos = rowptr[r] + atomicAdd(&cursor[r], 1);
        colval[pos] = make_int2(col[i], __float_as_int(val[i]));
    }
}

// 4) out[0:NM] = emb0 (concat), out[NM:2NM] = 0.25*emb0 (acc init)
__global__ void init_out_kernel(const float4* __restrict__ ue, const float4* __restrict__ ie,
                                float4* __restrict__ out) {
    const int NM4 = NM / 4;
    const int U4  = U_N * DIM / 4;
    int i = blockIdx.x * blockDim.x + threadIdx.x;
    int stride = gridDim.x * blockDim.x;
    for (; i < NM4; i += stride) {
        float4 v = (i < U4) ? ue[i] : ie[i - U4];
        out[i] = v;
        float4 w;
        w.x = 0.25f * v.x; w.y = 0.25f * v.y; w.z = 0.25f * v.z; w.w = 0.25f * v.w;
        out[NM4 + i] = w;
    }
}

// 5) SpMM: one wave per row, lane = dim. acc += 0.25*y fused.
template <bool WRITE_Y>
__global__ __launch_bounds__(256) void spmm_kernel(const int* __restrict__ rowptr,
                                                   const int2* __restrict__ colval,
                                                   const float* __restrict__ xin,
                                                   float* __restrict__ yout,
                                                   float* __restrict__ acc) {
    int row = blockIdx.x * 4 + (threadIdx.x >> 6);
    if (row >= NTOT) return;
    int lane = threadIdx.x & 63;
    // wave-uniform bounds -> scalar loads for (col,val) stream
    int s = __builtin_amdgcn_readfirstlane(rowptr[row]);
    int e = __builtin_amdgcn_readfirstlane(rowptr[row + 1]);
    float a = 0.f;
    int i = s;
    for (; i + 4 <= e; i += 4) {            // 4 independent gathers in flight
        int2 cv0 = colval[i];
        int2 cv1 = colval[i + 1];
        int2 cv2 = colval[i + 2];
        int2 cv3 = colval[i + 3];
        float g0 = xin[(cv0.x << 6) + lane];
        float g1 = xin[(cv1.x << 6) + lane];
        float g2 = xin[(cv2.x << 6) + lane];
        float g3 = xin[(cv3.x << 6) + lane];
        a = fmaf(__int_as_float(cv0.y), g0, a);
        a = fmaf(__int_as_float(cv1.y), g1, a);
        a = fmaf(__int_as_float(cv2.y), g2, a);
        a = fmaf(__int_as_float(cv3.y), g3, a);
    }
    for (; i < e; ++i) {
        int2 cv = colval[i];
        a = fmaf(__int_as_float(cv.y), xin[(cv.x << 6) + lane], a);
    }
    int o = (row << 6) + lane;
    if (WRITE_Y) yout[o] = a;
    acc[o] += 0.25f * a;                     // row owned by this wave: no atomic
}

// ---------------------------------------------------------------------------
extern "C" void kernel_launch(void* const* d_in, const int* in_sizes, int n_in,
                              void* d_out, int out_size, void* d_ws, size_t ws_size,
                              hipStream_t stream) {
    const float* ue  = (const float*)d_in[0];   // [100000,64]
    const float* ie  = (const float*)d_in[1];   // [50000,64]
    const float* val = (const float*)d_in[2];   // [4.8M]
    const int*   row = (const int*)d_in[3];     // [4.8M]
    const int*   col = (const int*)d_in[4];     // [4.8M]
    float* out = (float*)d_out;                 // [2*NM]: emb0 | light_out

    // workspace partition (~116.5 MB)
    char* ws = (char*)d_ws;
    size_t off = 0;
    auto alloc = [&](size_t bytes) -> void* {
        void* p = ws + off;
        off += (bytes + 511) & ~(size_t)511;
        return p;
    };
    int*  rowptr = (int*)alloc((NTOT + 1) * sizeof(int));
    int*  counts = (int*)alloc(NTOT * sizeof(int));
    int*  cursor = (int*)alloc(NTOT * sizeof(int));
    int*  bsum   = (int*)alloc(SCAN_T * sizeof(int));
    int*  boff   = (int*)alloc(SCAN_T * sizeof(int));
    int2* colval = (int2*)alloc((size_t)NNZ * sizeof(int2));
    float* bufA  = (float*)alloc((size_t)NM * sizeof(float));
    float* bufB  = (float*)alloc((size_t)NM * sizeof(float));
    (void)ws_size; (void)in_sizes; (void)n_in; (void)out_size;

    hipMemsetAsync(counts, 0, NTOT * sizeof(int), stream);
    hipMemsetAsync(cursor, 0, NTOT * sizeof(int), stream);

    // CSR build (counting sort by row)
    hist_kernel<<<2048, 256, 0, stream>>>(row, counts);
    scan_reduce<<<SCAN_NB, SCAN_T, 0, stream>>>(counts, bsum);
    scan_partials<<<1, SCAN_T, 0, stream>>>(bsum, boff, rowptr);
    scan_final<<<SCAN_NB, SCAN_T, 0, stream>>>(counts, boff, rowptr);
    scatter_kernel<<<2048, 256, 0, stream>>>(row, col, val, rowptr, cursor, colval);

    // emb0 -> out[0:NM]; acc=0.25*emb0 -> out[NM:2NM]
    init_out_kernel<<<2048, 256, 0, stream>>>((const float4*)ue, (const float4*)ie,
                                              (float4*)out);

    float* out2 = out + NM;
    const int SPMM_GRID = (NTOT + 3) / 4;     // 4 rows (waves) per 256-thread block
    // layer 1: gather from emb0 (= first half of out)
    spmm_kernel<true ><<<SPMM_GRID, 256, 0, stream>>>(rowptr, colval, out,  bufA,    out2);
    // layer 2
    spmm_kernel<true ><<<SPMM_GRID, 256, 0, stream>>>(rowptr, colval, bufA, bufB,    out2);
    // layer 3: only accumulate into out2
    spmm_kernel<false><<<SPMM_GRID, 256, 0, stream>>>(rowptr, colval, bufB, nullptr, out2);
}